// Round 10
// baseline (440.316 us; speedup 1.0000x reference)
//
#include <hip/hip_runtime.h>
#include <math.h>

constexpr int B = 4;
constexpr int N = 8192;
constexpr int KNN = 8;
constexpr int BINS = 512;   // 8x8x8 grid over [-4,4]^3, width-1 cells
constexpr int WPB = 4;      // waves per block

// cell id from point coords (clamped). Morton order for spatial locality of
// consecutive ids. Same function everywhere -> identical rounding/codes.
__device__ __forceinline__ int cell_of(float x, float y, float z) {
  int cx = min(max((int)floorf(x + 4.0f), 0), 7);
  int cy = min(max((int)floorf(y + 4.0f), 0), 7);
  int cz = min(max((int)floorf(z + 4.0f), 0), 7);
  int c = 0;
#pragma unroll
  for (int b = 0; b < 3; ++b)
    c |= (((cx >> b) & 1) << (3 * b + 2)) | (((cy >> b) & 1) << (3 * b + 1)) |
         (((cz >> b) & 1) << (3 * b + 0));
  return c;
}

__device__ __forceinline__ void load_point(const float* __restrict__ src,
                                           const float* __restrict__ tgt,
                                           const float* __restrict__ flow,
                                           int a, int i, float& x, float& y,
                                           float& z) {
  int arr = a >> 2, batch = a & 3;
  const float* base = (arr == 0 ? src : tgt) + batch * N * 3;
  x = base[3 * i]; y = base[3 * i + 1]; z = base[3 * i + 2];
  if (arr == 0) {
    const float* fb = flow + batch * N * 3;
    x += fb[3 * i]; y += fb[3 * i + 1]; z += fb[3 * i + 2];
  }
}

// K1: histogram of cell occupancy for all 8 (array,batch) point sets.
__global__ __launch_bounds__(256) void hist_kernel(
    const float* __restrict__ src, const float* __restrict__ tgt,
    const float* __restrict__ flow, int* __restrict__ hist,
    float* __restrict__ out) {
  int idx = blockIdx.x * 256 + threadIdx.x;  // 65536
  if (idx == 0) out[0] = 0.0f;
  int a = idx >> 13, i = idx & (N - 1);
  float x, y, z;
  load_point(src, tgt, flow, a, i, x, y, z);
  atomicAdd(&hist[a * BINS + cell_of(x, y, z)], 1);
}

// K2: per-array exclusive scan -> cell_start[a][513]; cnt[a][512] = start.
__global__ __launch_bounds__(512) void scan_kernel(
    const int* __restrict__ hist, int* __restrict__ cstart,
    int* __restrict__ cnt) {
  int a = threadIdx.x >> 6, lane = threadIdx.x & 63;
  if (lane == 0) cstart[a * (BINS + 1)] = 0;
  int carry = 0;
  for (int k = 0; k < 8; ++k) {
    int bin = k * 64 + lane;
    int v = hist[a * BINS + bin];
    int incl = v;
#pragma unroll
    for (int off = 1; off < 64; off <<= 1) {
      int n = __shfl_up(incl, off);
      if (lane >= off) incl += n;
    }
    cstart[a * (BINS + 1) + bin + 1] = carry + incl;
    cnt[a * BINS + bin] = carry + incl - v;
    carry += __shfl(incl, 63);
  }
}

// K3: scatter points (packed x,y,z,|p|^2/2) into cell-sorted order.
__global__ __launch_bounds__(256) void scatter_kernel(
    const float* __restrict__ src, const float* __restrict__ tgt,
    const float* __restrict__ flow, int* __restrict__ cnt,
    float4* __restrict__ sorted) {
  int idx = blockIdx.x * 256 + threadIdx.x;
  int a = idx >> 13, i = idx & (N - 1);
  float x, y, z;
  load_point(src, tgt, flow, a, i, x, y, z);
  int dest = atomicAdd(&cnt[a * BINS + cell_of(x, y, z)], 1);
  sorted[a * N + dest] = make_float4(x, y, z, 0.5f * (x * x + y * y + z * z));
}

// K4: actual AABB per cell (handles clamped boundary cells whose points lie
// outside the nominal box — nominal boxes would make pruning UNSAFE).
// Empty cells: lo=+INF, hi=-INF -> header distance = +INF -> never passes.
__global__ __launch_bounds__(256) void aabb_kernel(
    const float4* __restrict__ sorted, const int* __restrict__ cstart,
    float4* __restrict__ aabb) {
  int g = blockIdx.x * 256 + threadIdx.x;  // 4096 cells
  int a = g >> 9, c = g & (BINS - 1);
  int s = cstart[a * (BINS + 1) + c], e = cstart[a * (BINS + 1) + c + 1];
  float lx = INFINITY, ly = INFINITY, lz = INFINITY;
  float hx = -INFINITY, hy = -INFINITY, hz = -INFINITY;
  for (int i = s; i < e; ++i) {
    float4 p = sorted[a * N + i];
    lx = fminf(lx, p.x); ly = fminf(ly, p.y); lz = fminf(lz, p.z);
    hx = fmaxf(hx, p.x); hy = fmaxf(hy, p.y); hz = fmaxf(hz, p.z);
  }
  aabb[g * 2 + 0] = make_float4(lx, ly, lz, 0.0f);
  aabb[g * 2 + 1] = make_float4(hx, hy, hz, 0.0f);
}

// Insert tv into sorted ascending d[0..7]: d'[0]=min(d0,tv), d'[i]=med3(...).
// Inserting +INF is an exact no-op (med3(a,b,INF)=b for a<=b).
__device__ __forceinline__ void insert8(float (&d)[KNN], float tv) {
  float n0 = fminf(d[0], tv);
  float n1 = __builtin_amdgcn_fmed3f(d[0], d[1], tv);
  float n2 = __builtin_amdgcn_fmed3f(d[1], d[2], tv);
  float n3 = __builtin_amdgcn_fmed3f(d[2], d[3], tv);
  float n4 = __builtin_amdgcn_fmed3f(d[3], d[4], tv);
  float n5 = __builtin_amdgcn_fmed3f(d[4], d[5], tv);
  float n6 = __builtin_amdgcn_fmed3f(d[5], d[6], tv);
  float n7 = __builtin_amdgcn_fmed3f(d[6], d[7], tv);
  d[0] = n0; d[1] = n1; d[2] = n2; d[3] = n3;
  d[4] = n4; d[5] = n5; d[6] = n6; d[7] = n7;
}

// One block (4 waves) per 64 sorted queries. Per lane: bootstrap on the
// query's OWN cell (divergent ~16-pt loop) -> frozen bound b. Wave w then
// scans cells c ≡ w (mod 4): per-lane AABB header vs r2=2*min(b,d[7])+q2,
// wave ballot; passing cells processed with wave-uniform broadcast loads.
// Dedup: own-cell candidates kept only in owner wave (c & 3 == wave);
// owner masks c==mycell to INF in main loop; others reset d after bootstrap.
__global__ __launch_bounds__(256, 4) void chamfer_kernel(
    const float4* __restrict__ sorted, const float4* __restrict__ aabb,
    const int* __restrict__ cstart, float* __restrict__ out) {
  int lane = threadIdx.x & 63;
  int wave = threadIdx.x >> 6;
  int qcid = blockIdx.x;               // [0, 1024)
  int dir = qcid >> 9;
  int batch = (qcid >> 7) & 3;
  int qc = qcid & 127;
  int qa = (dir ? 4 : 0) + batch;
  int ca = (dir ? 0 : 4) + batch;
  const float4* __restrict__ qarr = sorted + qa * N;
  const float4* __restrict__ parr = sorted + ca * N;
  const float4* __restrict__ ab = aabb + ca * (2 * BINS);
  const int* __restrict__ cs = cstart + ca * (BINS + 1);

  float4 q = qarr[qc * 64 + lane];
  float q2 = 2.0f * q.w;
  float nqx = -q.x, nqy = -q.y, nqz = -q.z;
  int mycell = cell_of(q.x, q.y, q.z);

  float d[KNN];
#pragma unroll
  for (int i = 0; i < KNN; ++i) d[i] = INFINITY;

  // bootstrap: per-lane own-cell scan (divergent trip counts, ~16 pts)
  int bs = cs[mycell], be = cs[mycell + 1];
  for (int i = bs; i < be; ++i) {
    float4 p = parr[i];
    float tv = __builtin_fmaf(nqx, p.x,
               __builtin_fmaf(nqy, p.y,
               __builtin_fmaf(nqz, p.z, p.w)));
    insert8(d, tv);
  }
  float b = d[KNN - 1];  // frozen per-lane global bound (rank-key units)
  bool owner = ((mycell & 3) == wave);
  if (!owner) {
#pragma unroll
    for (int i = 0; i < KNN; ++i) d[i] = INFINITY;
  }

  // main: wave's cell partition with per-lane AABB pruning + wave ballot
  for (int c = wave; c < BINS; c += WPB) {
    float4 lo = ab[2 * c], hi = ab[2 * c + 1];  // wave-uniform
    float ax = fmaxf(fmaxf(lo.x - q.x, q.x - hi.x), 0.0f);
    float ay = fmaxf(fmaxf(lo.y - q.y, q.y - hi.y), 0.0f);
    float az = fmaxf(fmaxf(lo.z - q.z, q.z - hi.z), 0.0f);
    float d2box = __builtin_fmaf(ax, ax, __builtin_fmaf(ay, ay, az * az));
    float r2 = __builtin_fmaf(2.0f, fminf(b, d[KNN - 1]), q2) + 1e-4f;
    if (__ballot(d2box < r2)) {
      bool self = (c == mycell);  // per-lane
      int s = cs[c], e = cs[c + 1];  // wave-uniform range -> broadcast loads
      int i = s;
      for (; i + 4 <= e; i += 4) {
        float4 p0 = parr[i], p1 = parr[i + 1], p2 = parr[i + 2], p3 = parr[i + 3];
        float t0 = __builtin_fmaf(nqx, p0.x, __builtin_fmaf(nqy, p0.y, __builtin_fmaf(nqz, p0.z, p0.w)));
        float t1 = __builtin_fmaf(nqx, p1.x, __builtin_fmaf(nqy, p1.y, __builtin_fmaf(nqz, p1.z, p1.w)));
        float t2 = __builtin_fmaf(nqx, p2.x, __builtin_fmaf(nqy, p2.y, __builtin_fmaf(nqz, p2.z, p2.w)));
        float t3 = __builtin_fmaf(nqx, p3.x, __builtin_fmaf(nqy, p3.y, __builtin_fmaf(nqz, p3.z, p3.w)));
        insert8(d, self ? INFINITY : t0);
        insert8(d, self ? INFINITY : t1);
        insert8(d, self ? INFINITY : t2);
        insert8(d, self ? INFINITY : t3);
      }
      for (; i < e; ++i) {
        float4 p = parr[i];
        float tv = __builtin_fmaf(nqx, p.x,
                   __builtin_fmaf(nqy, p.y,
                   __builtin_fmaf(nqz, p.z, p.w)));
        insert8(d, self ? INFINITY : tv);
      }
    }
  }

  // merge 4 waves' top-8 per query through LDS
  __shared__ float part[WPB][64][KNN + 1];
#pragma unroll
  for (int i = 0; i < KNN; ++i) part[wave][lane][i] = d[i];
  __syncthreads();

  if (wave == 0) {
    float m[KNN];
#pragma unroll
    for (int i = 0; i < KNN; ++i) m[i] = part[0][lane][i];
#pragma unroll
    for (int s = 1; s < WPB; ++s)
#pragma unroll
      for (int i = 0; i < KNN; ++i) insert8(m, part[s][lane][i]);
    float s_ = 0.0f;
#pragma unroll
    for (int i = 0; i < KNN; ++i) {
      float d2 = fmaxf(__builtin_fmaf(2.0f, m[i], q2), 0.0f);
      s_ += sqrtf(d2);
    }
    float val = s_ * (1.0f / KNN);
    for (int off = 32; off; off >>= 1) val += __shfl_down(val, off, 64);
    if (lane == 0) atomicAdd(out, val * (1.0f / (B * N)));
  }
}

extern "C" void kernel_launch(void* const* d_in, const int* in_sizes, int n_in,
                              void* d_out, int out_size, void* d_ws, size_t ws_size,
                              hipStream_t stream) {
  const float* src = (const float*)d_in[0];
  const float* tgt = (const float*)d_in[1];
  const float* flow = (const float*)d_in[2];
  float* out = (float*)d_out;

  float4* sorted = (float4*)d_ws;                      // 8*8192*16 = 1 MB
  float4* aabb = sorted + 8 * N;                       // 8*512*2*16 = 256 KB
  int* hist = (int*)(aabb + 8 * BINS * 2);             // 8*512*4 = 16 KB
  int* cnt = hist + 8 * BINS;                          // 16 KB
  int* cstart = cnt + 8 * BINS;                        // 8*513*4 ≈ 16.4 KB

  hipMemsetAsync(hist, 0, 8 * BINS * sizeof(int), stream);
  hist_kernel<<<256, 256, 0, stream>>>(src, tgt, flow, hist, out);
  scan_kernel<<<1, 512, 0, stream>>>(hist, cstart, cnt);
  scatter_kernel<<<256, 256, 0, stream>>>(src, tgt, flow, cnt, sorted);
  aabb_kernel<<<16, 256, 0, stream>>>(sorted, cstart, aabb);
  chamfer_kernel<<<2 * B * (N / 64), 256, 0, stream>>>(sorted, aabb, cstart, out);
}